// Round 11
// baseline (464.500 us; speedup 1.0000x reference)
//
#include <hip/hip_runtime.h>
#include <hip/hip_bf16.h>
#include <stdint.h>

#define B_ 32
#define S_ 577
#define D_ 768
#define H_ 12
#define FF_ 3072
#define MROWS (B_*S_)   // 18464

typedef __attribute__((ext_vector_type(8))) short sh8;
typedef __attribute__((ext_vector_type(4))) float f32x4;
typedef __attribute__((ext_vector_type(4))) unsigned short us4;

static __device__ __forceinline__ unsigned short f2b(float f) {
  __hip_bfloat16 h = __float2bfloat16(f);
  return *reinterpret_cast<unsigned short*>(&h);
}
static __device__ __forceinline__ float b2f(unsigned short u) {
  __hip_bfloat16 h;
  *reinterpret_cast<unsigned short*>(&h) = u;
  return __bfloat162float(h);
}

// Branch-free exact-GELU: 0.5*v*(1+erf(v/sqrt2)) with erf via A&S 7.1.26.
// |err(erf)| <= 1.5e-7 -> ~1e-7 output err, 5 orders below bf16 rounding.
static __device__ __forceinline__ float fast_gelu(float v) {
  const float z = fabsf(v) * 0.70710678118f;
  const float t = __builtin_amdgcn_rcpf(__builtin_fmaf(0.3275911f, z, 1.0f));
  float p = 1.061405429f;
  p = __builtin_fmaf(p, t, -1.453152027f);
  p = __builtin_fmaf(p, t,  1.421413741f);
  p = __builtin_fmaf(p, t, -0.284496736f);
  p = __builtin_fmaf(p, t,  0.254829592f);
  p = p * t;
  const float e = __expf(-z * z);
  const float erf_abs = __builtin_fmaf(-p, e, 1.0f);   // erf(|x|)
  const float erf_v = copysignf(erf_abs, v);
  const float hv = 0.5f * v;
  return __builtin_fmaf(hv, erf_v, hv);                // 0.5v*(1+erf)
}

#define GLOAD_LDS16(gp, lp) \
  __builtin_amdgcn_global_load_lds((const __attribute__((address_space(1))) unsigned int*)(gp), \
                                   (__attribute__((address_space(3))) unsigned int*)(lp), 16, 0, 0)

// ---------------------------------------------------------------------------
// Unified pack + LN1 kernel: all weight transposes, bias pack, AND the first
// LayerNorm in ONE launch (they are mutually independent; saves launch gaps).
// ---------------------------------------------------------------------------
static __device__ __forceinline__ void packT_body(
    const float* __restrict__ src, unsigned short* __restrict__ dst,
    int K, int N, int kb, int nb, float scl, int tid)
{
  __shared__ unsigned short t[64][65];
  const int c = tid & 63, r4 = tid >> 6;
#pragma unroll
  for (int p = 0; p < 16; ++p) {
    const int ko = p * 4 + r4;
    t[c][ko] = f2b(src[(size_t)(kb + ko) * N + nb + c] * scl);
  }
  __syncthreads();
#pragma unroll
  for (int p = 0; p < 16; ++p) {
    const int rr = p * 4 + r4;
    dst[(size_t)(nb + rr) * K + kb + c] = t[rr][c];
  }
}

// LN body usable inside a 256-thread block (192 active lanes do f32x4 work).
static __device__ __forceinline__ void ln_body256(
    const float* __restrict__ x, const float* __restrict__ w,
    const float* __restrict__ bse, unsigned short* __restrict__ out,
    int row, int tid)
{
  __shared__ float red[6];
  const int wv = tid >> 6, ln = tid & 63;
  f32x4 v = {};
  float s = 0.f, ss = 0.f;
  if (tid < 192) {
    v = *(const f32x4*)(x + (size_t)row * 768 + tid * 4);
    s  = v[0] + v[1] + v[2] + v[3];
    ss = v[0]*v[0] + v[1]*v[1] + v[2]*v[2] + v[3]*v[3];
  }
#pragma unroll
  for (int off = 32; off >= 1; off >>= 1) {
    s  += __shfl_xor(s, off);
    ss += __shfl_xor(ss, off);
  }
  if (ln == 0 && wv < 3) { red[wv] = s; red[wv + 3] = ss; }
  __syncthreads();
  if (tid < 192) {
    s  = red[0] + red[1] + red[2];
    ss = red[3] + red[4] + red[5];
    const float mu = s * (1.f / 768.f);
    const float var = ss * (1.f / 768.f) - mu * mu;
    const float rs = rsqrtf(var + 1e-5f);
    const f32x4 w4 = *(const f32x4*)(w + tid * 4);
    const f32x4 b4 = *(const f32x4*)(bse + tid * 4);
    us4 o;
#pragma unroll
    for (int e = 0; e < 4; ++e) o[e] = f2b((v[e] - mu) * rs * w4[e] + b4[e]);
    *(us4*)(out + (size_t)row * 768 + tid * 4) = o;
  }
}

__global__ __launch_bounds__(256) void pack_ln(
    const float* __restrict__ Wq, const float* __restrict__ Wk,
    const float* __restrict__ Wv, const float* __restrict__ Wo,
    const float* __restrict__ W1, const float* __restrict__ W2,
    const float* __restrict__ bq, const float* __restrict__ bk,
    const float* __restrict__ bv,
    unsigned short* __restrict__ wqkvT, unsigned short* __restrict__ woT,
    unsigned short* __restrict__ w1T, unsigned short* __restrict__ w2T,
    float* __restrict__ biasq,
    const float* __restrict__ x, const float* __restrict__ ln1w,
    const float* __restrict__ ln1b, unsigned short* __restrict__ hbf)
{
  const int b = blockIdx.x;
  const int tid = threadIdx.x;
  if (b < 144) {                       // Wo [768][768] -> woT[768][768]
    packT_body(Wo, woT, 768, 768, (b / 12) * 64, (b % 12) * 64, 1.f, tid);
  } else if (b < 720) {                // W1 [768][3072] -> w1T[3072][768]
    const int i = b - 144;
    packT_body(W1, w1T, 768, 3072, (i / 48) * 64, (i % 48) * 64, 1.f, tid);
  } else if (b < 1296) {               // W2 [3072][768] -> w2T[768][3072]
    const int i = b - 720;
    packT_body(W2, w2T, 3072, 768, (i / 12) * 64, (i % 12) * 64, 1.f, tid);
  } else if (b < 1728) {               // Wq/Wk/Wv per-head [768][64] -> [64][768]
    const int i = b - 1296;
    const int kb = i % 12, h = (i / 12) % 12, which = i / 144;
    const float* src = ((which == 0) ? Wq : (which == 1) ? Wk : Wv) + (size_t)h * 768 * 64;
    unsigned short* db = wqkvT + (size_t)(which * 768 + h * 64) * 768;
    // Q pre-scaled by 1/8 (pow2 -> bit-exact); removes 1/sqrt(Dh) from attn
    packT_body(src, db, 768, 64, kb * 64, 0, which == 0 ? 0.125f : 1.f, tid);
  } else if (b < 1737) {               // bias pack (9 blocks)
    const int idx = (b - 1728) * 256 + tid;
    if (idx < 2304) {
      const int wb = idx / 768, rb = idx - wb * 768;
      const float* bb = (wb == 0) ? bq : (wb == 1) ? bk : bv;
      biasq[idx] = bb[rb] * (wb == 0 ? 0.125f : 1.f);
    }
  } else {                             // LN1 rows (18464 blocks)
    ln_body256(x, ln1w, ln1b, hbf, b - 1737, tid);
  }
}

// ---------------------------------------------------------------------------
// Standalone LN (for LN2, which depends on the Wo GEMM output).
// ---------------------------------------------------------------------------
__global__ __launch_bounds__(192) void ln_bf16(
    const float* __restrict__ x, const float* __restrict__ w, const float* __restrict__ bse,
    unsigned short* __restrict__ out)
{
  const int row = blockIdx.x;
  const int tid = threadIdx.x;
  const float* xr = x + (size_t)row * 768;
  const f32x4 v = *(const f32x4*)(xr + tid * 4);
  float s  = v[0] + v[1] + v[2] + v[3];
  float ss = v[0]*v[0] + v[1]*v[1] + v[2]*v[2] + v[3]*v[3];
#pragma unroll
  for (int off = 32; off >= 1; off >>= 1) {
    s  += __shfl_xor(s, off);
    ss += __shfl_xor(ss, off);
  }
  __shared__ float red[6];
  const int wv = tid >> 6, ln = tid & 63;
  if (ln == 0) { red[wv] = s; red[wv + 3] = ss; }
  __syncthreads();
  s  = red[0] + red[1] + red[2];
  ss = red[3] + red[4] + red[5];
  const float mu = s * (1.f / 768.f);
  const float var = ss * (1.f / 768.f) - mu * mu;
  const float rs = rsqrtf(var + 1e-5f);
  const f32x4 w4 = *(const f32x4*)(w + tid * 4);
  const f32x4 b4 = *(const f32x4*)(bse + tid * 4);
  us4 o;
#pragma unroll
  for (int e = 0; e < 4; ++e) o[e] = f2b((v[e] - mu) * rs * w4[e] + b4[e]);
  *(us4*)(out + (size_t)row * 768 + tid * 4) = o;
}

// ---------------------------------------------------------------------------
// m97-style occupancy-first GEMM: 128x128 tile, BK=64, 256 thr = 4 waves.
// At the measured structural ceiling for K=768 (789 TF; dbuf/8-phase/2-wave/
// TM=64 all regressed — rounds 1,2,6,8). L2-windowed tile order + bijective
// XCD chunking.
// EPI 0: bf16 out.  EPI 1: fp32 out + residual.  EPI 2: bf16 out + GELU.
// ---------------------------------------------------------------------------
template<int EPI>
__global__ __launch_bounds__(256, 4) void gemm128(
    const unsigned short* __restrict__ A, const unsigned short* __restrict__ Bt,
    const float* __restrict__ bias, const float* __restrict__ res,
    unsigned short* __restrict__ obf, float* __restrict__ of32,
    int M, int N, int K)
{
  __shared__ __align__(16) unsigned short sAB[2][128 * 64];  // A, B: 16 KiB each
  const int tid = threadIdx.x;
  const int wid = tid >> 6, ln = tid & 63;
  const int wr = wid >> 1, wc = wid & 1;
  const int l15 = ln & 15, lg = ln >> 4;
  const int l7 = l15 & 7;
  const int uo0 = ((lg) ^ l7) * 8;        // swizzled short-offset, kk=0
  const int uo1 = ((4 + lg) ^ l7) * 8;    // kk=1
  const int srow = ln >> 3;               // 0..7
  const int scol = ((ln & 7) ^ srow) * 8; // inverse-swizzled global col
  const int NT = K >> 6;

  // bijective XCD-chunked tile assignment (m204)
  const int gx = N >> 7;
  const int gm = (M + 127) >> 7;
  const int nwg = gridDim.x;
  const int q = nwg >> 3, r = nwg & 7;
  const int x = blockIdx.x & 7, ii = blockIdx.x >> 3;
  const int wg = (x < r ? x * (q + 1) : r * (q + 1) + (x - r) * q) + ii;
  // L2-window order: bn groups of 8, group-major -> bm -> bn  (bijective)
  int bm, bn;
  {
    const int g8 = gx >> 3, rem = gx & 7;
    const int per_full = gm << 3;
    if (wg < g8 * per_full) {
      const int bg = wg / per_full;
      const int r2 = wg - bg * per_full;
      bm = r2 >> 3; bn = (bg << 3) + (r2 & 7);
    } else {
      const int r2 = wg - g8 * per_full;
      bm = r2 / rem; bn = (g8 << 3) + (r2 - bm * rem);
    }
  }

  const int arow = wr * 64 + l15;
  const int brow = wc * 64 + l15;

  // strength-reduced staging: row pointers computed once, +64 per K-step
  const unsigned short* ap[4];
  const unsigned short* bp[4];
#pragma unroll
  for (int j = 0; j < 4; ++j) {
    int ga = bm * 128 + (wid * 4 + j) * 8 + srow; if (ga >= M) ga = M - 1;
    ap[j] = A + (size_t)ga * K + scol;
    const int gb = bn * 128 + (wid * 4 + j) * 8 + srow;
    bp[j] = Bt + (size_t)gb * K + scol;
  }
  unsigned short* const lA = sAB[0] + wid * 4 * 512;
  unsigned short* const lB = sAB[1] + wid * 4 * 512;

  f32x4 acc[4][4] = {};

  for (int t = 0; t < NT; ++t) {
    __syncthreads();   // all waves done reading previous tile
#pragma unroll
    for (int j = 0; j < 4; ++j) { GLOAD_LDS16(ap[j], lA + j * 512); ap[j] += 64; }
#pragma unroll
    for (int j = 0; j < 4; ++j) { GLOAD_LDS16(bp[j], lB + j * 512); bp[j] += 64; }
    asm volatile("s_waitcnt vmcnt(0)" ::: "memory");
    __syncthreads();

#pragma unroll
    for (int kk = 0; kk < 2; ++kk) {
      const int uo = kk ? uo1 : uo0;
      sh8 af[4], bf[4];
#pragma unroll
      for (int mi = 0; mi < 4; ++mi)
        af[mi] = *(const sh8*)(sAB[0] + (arow + mi * 16) * 64 + uo);
#pragma unroll
      for (int ni = 0; ni < 4; ++ni)
        bf[ni] = *(const sh8*)(sAB[1] + (brow + ni * 16) * 64 + uo);
#pragma unroll
      for (int mi = 0; mi < 4; ++mi)
#pragma unroll
        for (int ni = 0; ni < 4; ++ni)
          acc[mi][ni] = __builtin_amdgcn_mfma_f32_16x16x32_bf16(af[mi], bf[ni], acc[mi][ni], 0, 0, 0);
    }
  }

  // ---- LDS-staged coalesced epilogue: 4 passes of 32 rows ----
  constexpr int ESTR = 132;               // f32 stride: 16B-aligned, bank-spread
  float* eps = (float*)sAB;               // 32*132*4 = 16,896 B <= 32,768
  const int ecol = (tid & 31) * 4;        // col invariant across pp/pass
  const int gcol = bn * 128 + ecol;
  const f32x4 bvh = *(const f32x4*)(bias + gcol);
  const int erow0 = tid >> 5;             // 0..7
#pragma unroll
  for (int pass = 0; pass < 4; ++pass) {
    __syncthreads();
    if (wr == (pass >> 1)) {
      const int mib = (pass & 1) * 2;
#pragma unroll
      for (int ml = 0; ml < 2; ++ml)
#pragma unroll
        for (int ni = 0; ni < 4; ++ni)
#pragma unroll
          for (int rr = 0; rr < 4; ++rr)
            eps[(ml * 16 + lg * 4 + rr) * ESTR + wc * 64 + ni * 16 + l15] = acc[mib + ml][ni][rr];
    }
    __syncthreads();
#pragma unroll
    for (int pp = 0; pp < 4; ++pp) {
      const int rl = pp * 8 + erow0;      // 0..31
      const int grow = bm * 128 + pass * 32 + rl;
      if (grow < M) {
        f32x4 v = *(const f32x4*)(eps + rl * ESTR + ecol);
        v += bvh;
        if (EPI == 2) {
#pragma unroll
          for (int e = 0; e < 4; ++e) v[e] = fast_gelu(v[e]);
        }
        if (EPI == 1) {
          const f32x4 rv = *(const f32x4*)(res + (size_t)grow * N + gcol);
          v += rv;
          *(f32x4*)(of32 + (size_t)grow * N + gcol) = v;
        } else {
          us4 o = { f2b(v[0]), f2b(v[1]), f2b(v[2]), f2b(v[3]) };
          *(us4*)(obf + (size_t)grow * N + gcol) = o;
        }
      }
    }
  }
}

// ---------------------------------------------------------------------------
// Flash attention, round 11: T14 async-stage (K/V of tile t+1 loaded into
// REGISTERS right after tile t's staging barrier -> global latency hides
// under softmax+PV; ds_write at next tile top) + post-sP barrier removed
// (sP[wv] is wave-private; same-wave ds_write->ds_read ordered by compiler
// lgkmcnt). Barriers/tile: 3 -> 2.
// ---------------------------------------------------------------------------
__global__ __launch_bounds__(512) void attn(
    const unsigned short* __restrict__ qkv, unsigned short* __restrict__ ctx)
{
  constexpr int KP = 72;
  __shared__ __align__(16) unsigned short sQ[128 * KP];
  __shared__ __align__(16) unsigned short sK[64 * KP];
  __shared__ __align__(16) unsigned short sVT[64 * KP];
  __shared__ __align__(16) unsigned short sP[8][16 * KP];
  const int tid = threadIdx.x, wv = tid >> 6, ln = tid & 63;
  const int l15 = ln & 15, lg = ln >> 4;
  const int b = blockIdx.z, h = blockIdx.y, qt = blockIdx.x;
  const size_t base = (size_t)b * S_ * 2304 + h * 64;
  const unsigned short* qp = qkv + base;
  const unsigned short* kp = qkv + base + 768;
  const unsigned short* vp = qkv + base + 1536;

  // Q staging: pure copy (weights pre-scaled by 1/8 in pack)
  {
    const int r = tid >> 2, c = (tid & 3) * 16;
    int row = qt * 128 + r; if (row >= S_) row = S_ - 1;
    const unsigned short* g = qp + (size_t)row * 2304 + c;
    *(sh8*)(sQ + r * KP + c)     = *(const sh8*)g;
    *(sh8*)(sQ + r * KP + c + 8) = *(const sh8*)(g + 8);
  }

  // staging geometry + fast-path pointers (+64*2304 per tile)
  const int kr = tid >> 3, kc = (tid & 7) * 8;
  const unsigned short* krow = kp + (size_t)kr * 2304 + kc;
  unsigned short* const sKdst = sK + kr * KP + kc;
  const int ve = tid & 63, vkvb = tid >> 6;
  const unsigned short* vrow = vp + (size_t)vkvb * 8 * 2304 + ve;
  unsigned short* const sVdst = sVT + ve * KP + vkvb * 8;

  const int nt = (S_ + 63) / 64;          // 10; tiles 0..8 are full
  // prologue: load tile 0 into registers (tile 0 is full, no clamps)
  sh8 kreg = *(const sh8*)krow;
  unsigned short vreg[8];
#pragma unroll
  for (int j = 0; j < 8; ++j) vreg[j] = vrow[(size_t)j * 2304];
  krow += (size_t)64 * 2304;
  vrow += (size_t)64 * 2304;

  f32x4 oacc[4] = {};
  float m_run = -1e30f, l_run = 0.f;
  for (int t = 0; t < nt; ++t) {
    __syncthreads();                      // all waves done reading sK/sVT(t-1)
    *(sh8*)sKdst = kreg;
    *(sh8*)sVdst = *(sh8*)vreg;
    __syncthreads();                      // staging visible

    // T14: issue next tile's global loads now; they fly during softmax+PV
    if (t + 1 < nt) {
      if (t + 1 < nt - 1) {               // fast path: no clamps
        kreg = *(const sh8*)krow;
#pragma unroll
        for (int j = 0; j < 8; ++j) vreg[j] = vrow[(size_t)j * 2304];
        krow += (size_t)64 * 2304;
        vrow += (size_t)64 * 2304;
      } else {                            // tail tile: clamped
        int row = (nt - 1) * 64 + kr; if (row >= S_) row = S_ - 1;
        kreg = *(const sh8*)(kp + (size_t)row * 2304 + kc);
#pragma unroll
        for (int j = 0; j < 8; ++j) {
          int rr = (nt - 1) * 64 + vkvb * 8 + j; if (rr >= S_) rr = S_ - 1;
          vreg[j] = vp[(size_t)rr * 2304 + ve];
        }
      }
    }

    f32x4 sacc[4] = {};
#pragma unroll
    for (int kk = 0; kk < 2; ++kk) {
      sh8 bq = *(const sh8*)(sQ + (wv * 16 + l15) * KP + kk * 32 + lg * 8);
#pragma unroll
      for (int f = 0; f < 4; ++f) {
        sh8 ak = *(const sh8*)(sK + (f * 16 + l15) * KP + kk * 32 + lg * 8);
        sacc[f] = __builtin_amdgcn_mfma_f32_16x16x32_bf16(ak, bq, sacc[f], 0, 0, 0);
      }
    }

    if (t == nt - 1) {
#pragma unroll
      for (int f = 0; f < 4; ++f)
#pragma unroll
        for (int r = 0; r < 4; ++r)
          if (t * 64 + f * 16 + lg * 4 + r >= S_) sacc[f][r] = -1e30f;
    }
    float pmax = -1e30f;
#pragma unroll
    for (int f = 0; f < 4; ++f)
#pragma unroll
      for (int r = 0; r < 4; ++r) pmax = fmaxf(pmax, sacc[f][r]);
    pmax = fmaxf(pmax, __shfl_xor(pmax, 16));
    pmax = fmaxf(pmax, __shfl_xor(pmax, 32));
    const float mnew = fmaxf(m_run, pmax);
    const float alpha = __expf(m_run - mnew);
    float psum = 0.f;
    unsigned short pb[4][4];
#pragma unroll
    for (int f = 0; f < 4; ++f)
#pragma unroll
      for (int r = 0; r < 4; ++r) {
        const float p = __expf(sacc[f][r] - mnew);
        psum += p;
        pb[f][r] = f2b(p);
      }
    psum += __shfl_xor(psum, 16);
    psum += __shfl_xor(psum, 32);
    l_run = l_run * alpha + psum;
    m_run = mnew;
#pragma unroll
    for (int f = 0; f < 4; ++f) {
      oacc[f][0] *= alpha; oacc[f][1] *= alpha;
      oacc[f][2] *= alpha; oacc[f][3] *= alpha;
    }
#pragma unroll
    for (int f = 0; f < 4; ++f) {
      us4 pk = { pb[f][0], pb[f][1], pb[f][2], pb[f][3] };
      *(us4*)(sP[wv] + l15 * KP + f * 16 + lg * 4) = pk;
    }
    // NO __syncthreads here: sP[wv] is wave-private; the same-wave
    // ds_write -> ds_read dependency is ordered by compiler lgkmcnt.

#pragma unroll
    for (int kk = 0; kk < 2; ++kk) {
      sh8 bp = *(const sh8*)(sP[wv] + l15 * KP + kk * 32 + lg * 8);
#pragma unroll
      for (int fe = 0; fe < 4; ++fe) {
        sh8 av = *(const sh8*)(sVT + (fe * 16 + l15) * KP + kk * 32 + lg * 8);
        oacc[fe] = __builtin_amdgcn_mfma_f32_16x16x32_bf16(av, bp, oacc[fe], 0, 0, 0);
      }
    }
  }

  const int qa = qt * 128 + wv * 16 + l15;
  if (qa < S_) {
    const float inv = 1.f / l_run;
    const size_t orow = ((size_t)b * S_ + qa) * 768 + h * 64;
#pragma unroll
    for (int fe = 0; fe < 4; ++fe) {
      unsigned short pk[4];
#pragma unroll
      for (int r = 0; r < 4; ++r) pk[r] = f2b(oacc[fe][r] * inv);
      *(us4*)(ctx + orow + fe * 16 + lg * 4) = *(us4*)pk;
    }
  }
}

// ---------------------------------------------------------------------------
extern "C" void kernel_launch(void* const* d_in, const int* in_sizes, int n_in,
                              void* d_out, int out_size, void* d_ws, size_t ws_size,
                              hipStream_t stream)
{
  const float* x    = (const float*)d_in[0];
  const float* ln1w = (const float*)d_in[1];
  const float* ln1b = (const float*)d_in[2];
  const float* Wq   = (const float*)d_in[3];
  const float* bq   = (const float*)d_in[4];
  const float* Wk   = (const float*)d_in[5];
  const float* bk   = (const float*)d_in[6];
  const float* Wv   = (const float*)d_in[7];
  const float* bv   = (const float*)d_in[8];
  const float* Wo   = (const float*)d_in[9];
  const float* bo   = (const float*)d_in[10];
  const float* ln2w = (const float*)d_in[11];
  const float* ln2b = (const float*)d_in[12];
  const float* W1   = (const float*)d_in[13];
  const float* b1   = (const float*)d_in[14];
  const float* W2   = (const float*)d_in[15];
  const float* b2   = (const float*)d_in[16];
  float* out = (float*)d_out;
  char* ws = (char*)d_ws;

  unsigned short* wqkvT = (unsigned short*)(ws + 0);          //  3,538,944
  unsigned short* woT   = (unsigned short*)(ws + 3538944);    //  1,179,648
  unsigned short* w1T   = (unsigned short*)(ws + 4718592);    //  4,718,592
  unsigned short* w2T   = (unsigned short*)(ws + 9437184);    //  4,718,592
  float*          biasq = (float*)(ws + 14155776);            //      9,216
  unsigned short* hbf   = (unsigned short*)(ws + 14164992);   // 28,360,704
  unsigned short* qkvb  = (unsigned short*)(ws + 42525696);   // 85,082,112
  unsigned short* ctxb  = (unsigned short*)(ws + 127607808);  // 28,360,704
  unsigned short* mlp1  = qkvb;   // overlays dead qkv+ctx

  // unified pack + LN1 launch (packs and LN1 are independent)
  pack_ln<<<1737 + MROWS, 256, 0, stream>>>(Wq, Wk, Wv, Wo, W1, W2, bq, bk, bv,
                                            wqkvT, woT, w1T, w2T, biasq,
                                            x, ln1w, ln1b, hbf);

  // 145 M-tiles of 128 (M=18464)
  gemm128<0><<<145 * 18, 256, 0, stream>>>(hbf, wqkvT, biasq, nullptr, qkvb, nullptr,
                                           MROWS, 2304, 768);
  attn<<<dim3(5, 12, 32), 512, 0, stream>>>(qkvb, ctxb);
  gemm128<1><<<145 * 6, 256, 0, stream>>>(ctxb, woT, bo, x, nullptr, out,
                                          MROWS, 768, 768);
  ln_bf16<<<MROWS, 192, 0, stream>>>(out, ln2w, ln2b, hbf);
  gemm128<2><<<145 * 24, 256, 0, stream>>>(hbf, w1T, b1, nullptr, mlp1, nullptr,
                                           MROWS, 3072, 768);
  gemm128<1><<<145 * 6, 256, 0, stream>>>(mlp1, w2T, b2, out, nullptr, out,
                                          MROWS, 768, 3072);
}